// Round 3
// baseline (274.616 us; speedup 1.0000x reference)
//
#include <hip/hip_runtime.h>

#define B_ 4
#define N_ 2048
#define F_IN 64
#define H_ 4
#define K_ 64
#define L2E 1.44269504088896f

typedef __attribute__((ext_vector_type(8))) short bf16x8;
typedef __attribute__((ext_vector_type(4))) float f32x4;

__device__ __forceinline__ unsigned short f2bf(float f) {
  unsigned u = __builtin_bit_cast(unsigned, f);
  u = (u + 0x7fffu + ((u >> 16) & 1u)) >> 16;
  return (unsigned short)u;
}

// ---------------------------------------------------------------------------
// Kernel 1: feats = x @ W per head (bf16 MFMA), scaled row scores
// (ss/sn pre-multiplied by log2(e) so the attention loop can use exp2),
// feats stored transposed bf16: featsT[bh][k][n].
// ---------------------------------------------------------------------------
#define WT_STRIDE 72

__global__ __launch_bounds__(256) void k_feats(
    const float* __restrict__ x, const float* __restrict__ W,
    const float* __restrict__ a_self, const float* __restrict__ a_neigh,
    unsigned short* __restrict__ featsT, float* __restrict__ ss,
    float* __restrict__ sn) {
  __shared__ __align__(16) unsigned short wt[K_ * WT_STRIDE];  // wt[col][f]
  const int b = blockIdx.z, h = blockIdx.y, n0 = blockIdx.x * 64;
  const int tid = threadIdx.x;
  const float* Wh = W + h * F_IN * K_;
  {
    const int f = tid & 63;
#pragma unroll
    for (int i = 0; i < 16; ++i) {
      const int k = (tid >> 6) + 4 * i;
      wt[k * WT_STRIDE + f] = f2bf(Wh[f * K_ + k]);  // wt[col=k][f]
    }
  }
  __syncthreads();
  const int wave = tid >> 6, lane = tid & 63;
  const int q = lane >> 4, rr = lane & 15;
  const int bh = b * H_ + h;
  const int arow = n0 + wave * 16 + rr;  // A-operand row = lane&15
  const float* xr = x + ((size_t)b * N_ + arow) * F_IN;
  f32x4 x0 = *(const f32x4*)(xr + q * 8);
  f32x4 x1 = *(const f32x4*)(xr + q * 8 + 4);
  f32x4 x2 = *(const f32x4*)(xr + 32 + q * 8);
  f32x4 x3 = *(const f32x4*)(xr + 32 + q * 8 + 4);
  bf16x8 a0, a1;
#pragma unroll
  for (int j = 0; j < 4; ++j) {
    a0[j] = (short)f2bf(x0[j]); a0[j + 4] = (short)f2bf(x1[j]);
    a1[j] = (short)f2bf(x2[j]); a1[j + 4] = (short)f2bf(x3[j]);
  }
  f32x4 acc[4];
#pragma unroll
  for (int c = 0; c < 4; ++c) acc[c] = (f32x4){0.f, 0.f, 0.f, 0.f};
#pragma unroll
  for (int c = 0; c < 4; ++c) {
    bf16x8 b0 = *(const bf16x8*)(&wt[(c * 16 + rr) * WT_STRIDE + q * 8]);
    bf16x8 b1 = *(const bf16x8*)(&wt[(c * 16 + rr) * WT_STRIDE + 32 + q * 8]);
    acc[c] = __builtin_amdgcn_mfma_f32_16x16x32_bf16(a0, b0, acc[c], 0, 0, 0);
    acc[c] = __builtin_amdgcn_mfma_f32_16x16x32_bf16(a1, b1, acc[c], 0, 0, 0);
  }
#pragma unroll
  for (int c = 0; c < 4; ++c) {
    const int col = c * 16 + rr;
    ushort4 v;
    v.x = f2bf(acc[c][0]); v.y = f2bf(acc[c][1]);
    v.z = f2bf(acc[c][2]); v.w = f2bf(acc[c][3]);
    *(ushort4*)(&featsT[((size_t)bh * K_ + col) * N_ + n0 + wave * 16 + q * 4]) = v;
  }
  float asv[4], anv[4];
#pragma unroll
  for (int c = 0; c < 4; ++c) {
    asv[c] = a_self[h * K_ + c * 16 + rr] * L2E;   // fold log2(e) into scores
    anv[c] = a_neigh[h * K_ + c * 16 + rr] * L2E;
  }
#pragma unroll
  for (int t = 0; t < 4; ++t) {
    float ps = 0.f, pn = 0.f;
#pragma unroll
    for (int c = 0; c < 4; ++c) { ps += acc[c][t] * asv[c]; pn += acc[c][t] * anv[c]; }
#pragma unroll
    for (int off = 8; off > 0; off >>= 1) {
      ps += __shfl_xor(ps, off);
      pn += __shfl_xor(pn, off);
    }
    if (rr == 0) {
      const int n = n0 + wave * 16 + q * 4 + t;  // C/D row = q*4+t
      ss[bh * N_ + n] = ps;
      sn[bh * N_ + n] = pn;
    }
  }
}

// ---------------------------------------------------------------------------
// Kernel 2a (head-fused, split-m): block = (b, 16-row tile, col-segment).
// wave = head. All 4 waves read the SAME adj/mask lines -> L1 reuse, 4x less
// L2-miss traffic than per-head blocks. Unnormalized single pass.
// ---------------------------------------------------------------------------
template <int P>
__global__ __launch_bounds__(256) void k_attn_part(
    const float* __restrict__ adj, const float* __restrict__ mask,
    const unsigned short* __restrict__ featsT, const float* __restrict__ ss,
    const float* __restrict__ sn, float* __restrict__ pacc,
    float* __restrict__ pZ, float* __restrict__ pe) {
  const int MSEG = N_ / P;
  __shared__ __align__(16) float sn_lds[H_][N_ / P];
  const int b = blockIdx.z;
  const int part = blockIdx.x % P, nt = blockIdx.x / P;
  const int tid = threadIdx.x;
  const int mbase = part * MSEG;
  for (int i = tid; i < H_ * MSEG; i += 256) {
    const int hh = i / MSEG, m = i % MSEG;
    sn_lds[hh][m] = sn[(b * H_ + hh) * N_ + mbase + m];
  }
  __syncthreads();
  const int wave = tid >> 6, lane = tid & 63;   // wave = head
  const int q = lane >> 4, rr = lane & 15;
  const int bh = b * H_ + wave;
  const int row = nt * 16 + rr;                 // A-operand row = lane&15
  const float ss_r = ss[bh * N_ + row];
  const float* adj_row = adj + ((size_t)b * N_ + row) * N_ + mbase;
  const float* mask_row = mask + ((size_t)b * N_ + row) * N_ + mbase;
  const unsigned short* v0 = featsT + ((size_t)bh * K_ + 0 + rr) * N_ + mbase;
  const unsigned short* v1 = featsT + ((size_t)bh * K_ + 16 + rr) * N_ + mbase;
  const unsigned short* v2 = featsT + ((size_t)bh * K_ + 32 + rr) * N_ + mbase;
  const unsigned short* v3 = featsT + ((size_t)bh * K_ + 48 + rr) * N_ + mbase;
  f32x4 acc0 = {0.f, 0.f, 0.f, 0.f}, acc1 = {0.f, 0.f, 0.f, 0.f};
  f32x4 acc2 = {0.f, 0.f, 0.f, 0.f}, acc3 = {0.f, 0.f, 0.f, 0.f};
  float Zp = 0.f, ep = 0.f;
  for (int m0 = 0; m0 < MSEG; m0 += 32) {
    const int mq = m0 + q * 8;
    f32x4 ad0 = *(const f32x4*)(adj_row + mq);
    f32x4 ad1 = *(const f32x4*)(adj_row + mq + 4);
    f32x4 k0 = *(const f32x4*)(mask_row + mq);
    f32x4 k1 = *(const f32x4*)(mask_row + mq + 4);
    f32x4 s0 = *(const f32x4*)(&sn_lds[wave][mq]);
    f32x4 s1 = *(const f32x4*)(&sn_lds[wave][mq + 4]);
    bf16x8 af;
#pragma unroll
    for (int j = 0; j < 8; ++j) {
      float snj = j < 4 ? s0[j] : s1[j - 4];
      float adjj = j < 4 ? ad0[j] : ad1[j - 4];
      float mj = j < 4 ? k0[j] : k1[j - 4];
      float t = ss_r + snj;                       // already scaled by log2e
      float sc = fmaxf(t, 0.2f * t);              // leaky (scale-invariant)
      float w = exp2f(fmaf(mj, L2E, sc));         // e^(orig score)
      Zp += w;
      float wa = w * adjj;
      ep += wa;
      af[j] = (short)f2bf(wa);
    }
    bf16x8 bf0 = *(const bf16x8*)(v0 + mq);
    bf16x8 bf1 = *(const bf16x8*)(v1 + mq);
    bf16x8 bf2 = *(const bf16x8*)(v2 + mq);
    bf16x8 bf3 = *(const bf16x8*)(v3 + mq);
    acc0 = __builtin_amdgcn_mfma_f32_16x16x32_bf16(af, bf0, acc0, 0, 0, 0);
    acc1 = __builtin_amdgcn_mfma_f32_16x16x32_bf16(af, bf1, acc1, 0, 0, 0);
    acc2 = __builtin_amdgcn_mfma_f32_16x16x32_bf16(af, bf2, acc2, 0, 0, 0);
    acc3 = __builtin_amdgcn_mfma_f32_16x16x32_bf16(af, bf3, acc3, 0, 0, 0);
  }
  Zp += __shfl_xor(Zp, 16); Zp += __shfl_xor(Zp, 32);
  ep += __shfl_xor(ep, 16); ep += __shfl_xor(ep, 32);
  if (q == 0) {
    pZ[(part * 16 + bh) * N_ + row] = Zp;
    pe[(part * 16 + bh) * N_ + row] = ep;
  }
#pragma unroll
  for (int t = 0; t < 4; ++t) {
    const int n = nt * 16 + q * 4 + t;  // C/D row = q*4+t
    float* pr = pacc + ((size_t)((part * 16 + bh) * N_ + n)) * 64;
    pr[rr]      = acc0[t];
    pr[16 + rr] = acc1[t];
    pr[32 + rr] = acc2[t];
    pr[48 + rr] = acc3[t];
  }
}

// ---------------------------------------------------------------------------
// Kernel 2b: combine P partials, normalize, bias + BN + ReLU, e_loss.
// (verbatim from R2 — proven) One block per (b,h,64-row tile).
// ---------------------------------------------------------------------------
template <int P>
__global__ __launch_bounds__(256) void k_reduce(
    const float* __restrict__ pacc, const float* __restrict__ pZ,
    const float* __restrict__ pe, const float* __restrict__ bias,
    float* __restrict__ act, float* __restrict__ eloss) {
  const int b = blockIdx.z, h = blockIdx.y, nt = blockIdx.x;
  const int bh = b * H_ + h, tid = threadIdx.x;
  __shared__ float zs[64], es[64];
  if (tid < 64) {
    float z = 0.f, e = 0.f;
#pragma unroll
    for (int p = 0; p < P; ++p) {
      z += pZ[(p * 16 + bh) * N_ + nt * 64 + tid];
      e += pe[(p * 16 + bh) * N_ + nt * 64 + tid];
    }
    zs[tid] = 1.f / z;
    es[tid] = e / z;
  }
  __syncthreads();
  const float INVS = 0.99950037468777323f;  // 1/sqrt(1+1e-3)
#pragma unroll
  for (int ee = 0; ee < 16; ++ee) {
    const int idx = ee * 256 + tid;
    const int rl = idx >> 6, col = idx & 63;
    float v = 0.f;
#pragma unroll
    for (int p = 0; p < P; ++p)
      v += pacc[(((p * 16 + bh) * 32 + nt) << 12) + idx];
    const int n = nt * 64 + rl;
    act[((size_t)(b * N_ + n)) * (H_ * K_) + h * K_ + col] =
        fmaxf(0.f, (v * zs[rl] + bias[h * K_ + col]) * INVS);
  }
  if (tid < 64) {
    float v = es[tid];
#pragma unroll
    for (int off = 32; off > 0; off >>= 1) v += __shfl_xor(v, off);
    if (tid == 0) atomicAdd(eloss + b, v * (1.f / N_));
  }
}

// ---------------------------------------------------------------------------
// Fallback (no workspace): direct per-head kernel, updated for scaled scores.
// ---------------------------------------------------------------------------
__global__ __launch_bounds__(256) void k_attn_direct(
    const float* __restrict__ adj, const float* __restrict__ mask,
    const unsigned short* __restrict__ featsT, const float* __restrict__ ss,
    const float* __restrict__ sn, const float* __restrict__ bias,
    float* __restrict__ act, float* __restrict__ eloss) {
  __shared__ __align__(16) float sn_lds[N_];
  __shared__ float red[64];
  const int b = blockIdx.z, h = blockIdx.y, nt = blockIdx.x;
  const int bh = b * H_ + h;
  const int tid = threadIdx.x;
  const float* snrow = sn + bh * N_;
  for (int i = tid; i < N_; i += 256) sn_lds[i] = snrow[i];
  __syncthreads();
  const int wave = tid >> 6, lane = tid & 63;
  const int q = lane >> 4, rr = lane & 15;
  const int row = nt * 64 + wave * 16 + rr;
  const float ss_r = ss[bh * N_ + row];
  const float* adj_row = adj + ((size_t)b * N_ + row) * N_;
  const float* mask_row = mask + ((size_t)b * N_ + row) * N_;
  const unsigned short* v0 = featsT + ((size_t)bh * K_ + 0 + rr) * N_;
  const unsigned short* v1 = featsT + ((size_t)bh * K_ + 16 + rr) * N_;
  const unsigned short* v2 = featsT + ((size_t)bh * K_ + 32 + rr) * N_;
  const unsigned short* v3 = featsT + ((size_t)bh * K_ + 48 + rr) * N_;
  f32x4 acc0 = {0.f, 0.f, 0.f, 0.f}, acc1 = {0.f, 0.f, 0.f, 0.f};
  f32x4 acc2 = {0.f, 0.f, 0.f, 0.f}, acc3 = {0.f, 0.f, 0.f, 0.f};
  float Zp = 0.f, ep = 0.f;
  for (int m0 = 0; m0 < N_; m0 += 32) {
    const int mq = m0 + q * 8;
    f32x4 ad0 = *(const f32x4*)(adj_row + mq);
    f32x4 ad1 = *(const f32x4*)(adj_row + mq + 4);
    f32x4 k0 = *(const f32x4*)(mask_row + mq);
    f32x4 k1 = *(const f32x4*)(mask_row + mq + 4);
    f32x4 s0 = *(const f32x4*)(&sn_lds[mq]);
    f32x4 s1 = *(const f32x4*)(&sn_lds[mq + 4]);
    bf16x8 af;
#pragma unroll
    for (int j = 0; j < 8; ++j) {
      float snj = j < 4 ? s0[j] : s1[j - 4];
      float adjj = j < 4 ? ad0[j] : ad1[j - 4];
      float mj = j < 4 ? k0[j] : k1[j - 4];
      float t = ss_r + snj;
      float sc = fmaxf(t, 0.2f * t);
      float w = exp2f(fmaf(mj, L2E, sc));
      Zp += w;
      float wa = w * adjj;
      ep += wa;
      af[j] = (short)f2bf(wa);
    }
    bf16x8 bf0 = *(const bf16x8*)(v0 + mq);
    bf16x8 bf1 = *(const bf16x8*)(v1 + mq);
    bf16x8 bf2 = *(const bf16x8*)(v2 + mq);
    bf16x8 bf3 = *(const bf16x8*)(v3 + mq);
    acc0 = __builtin_amdgcn_mfma_f32_16x16x32_bf16(af, bf0, acc0, 0, 0, 0);
    acc1 = __builtin_amdgcn_mfma_f32_16x16x32_bf16(af, bf1, acc1, 0, 0, 0);
    acc2 = __builtin_amdgcn_mfma_f32_16x16x32_bf16(af, bf2, acc2, 0, 0, 0);
    acc3 = __builtin_amdgcn_mfma_f32_16x16x32_bf16(af, bf3, acc3, 0, 0, 0);
  }
  Zp += __shfl_xor(Zp, 16); Zp += __shfl_xor(Zp, 32);
  ep += __shfl_xor(ep, 16); ep += __shfl_xor(ep, 32);
  const float rz = 1.f / Zp;
  const float b0v = bias[h * K_ + rr], b1v = bias[h * K_ + 16 + rr];
  const float b2v = bias[h * K_ + 32 + rr], b3v = bias[h * K_ + 48 + rr];
  const float INVS = 0.99950037468777323f;
#pragma unroll
  for (int t = 0; t < 4; ++t) {
    const float rzt = __shfl(rz, q * 4 + t);
    const int n = nt * 64 + wave * 16 + q * 4 + t;
    float* orow = act + ((size_t)b * N_ + n) * (H_ * K_) + h * K_;
    orow[rr]      = fmaxf(0.f, (acc0[t] * rzt + b0v) * INVS);
    orow[16 + rr] = fmaxf(0.f, (acc1[t] * rzt + b1v) * INVS);
    orow[32 + rr] = fmaxf(0.f, (acc2[t] * rzt + b2v) * INVS);
    orow[48 + rr] = fmaxf(0.f, (acc3[t] * rzt + b3v) * INVS);
  }
  if (q == 0) red[wave * 16 + rr] = ep * rz;
  __syncthreads();
  if (wave == 0) {
    float v = red[lane];
#pragma unroll
    for (int off = 32; off > 0; off >>= 1) v += __shfl_xor(v, off);
    if (lane == 0) atomicAdd(eloss + b, v * (1.f / N_));
  }
}

extern "C" void kernel_launch(void* const* d_in, const int* in_sizes, int n_in,
                              void* d_out, int out_size, void* d_ws, size_t ws_size,
                              hipStream_t stream) {
  const float* x      = (const float*)d_in[0];
  const float* adj    = (const float*)d_in[1];
  const float* mask   = (const float*)d_in[2];
  const float* W      = (const float*)d_in[3];
  const float* a_self = (const float*)d_in[4];
  const float* a_neigh= (const float*)d_in[5];
  const float* bias   = (const float*)d_in[6];
  float* act = (float*)d_out;
  float* uloss = act + (size_t)B_ * N_ * H_ * K_;
  float* eloss = uloss + B_;

  constexpr int P = 4;
  const size_t featsBytes = (size_t)B_ * H_ * K_ * N_ * 2;              // 4 MB
  const size_t sBytes = (size_t)B_ * H_ * N_ * 4;                       // 128 KB
  const size_t paccBytes = (size_t)P * B_ * H_ * N_ * 64 * 4;           // 32 MB
  const size_t pzBytes = (size_t)P * B_ * H_ * N_ * 4;                  // 512 KB

  unsigned short* featsT = (unsigned short*)d_ws;
  char* p = (char*)d_ws + featsBytes;
  float* ss = (float*)p; p += sBytes;
  float* sn = (float*)p; p += sBytes;
  float* pacc = (float*)p; p += paccBytes;
  float* pZ = (float*)p; p += pzBytes;
  float* pe = (float*)p; p += pzBytes;
  const size_t need = (size_t)(p - (char*)d_ws);

  // u_loss is identically 0 (counts == deg elementwise); also zeroes eloss[4].
  hipMemsetAsync(uloss, 0, 8 * sizeof(float), stream);

  k_feats<<<dim3(N_ / 64, H_, B_), 256, 0, stream>>>(x, W, a_self, a_neigh,
                                                     featsT, ss, sn);
  if (ws_size >= need) {
    // head-fused: grid.x = row-tiles (N/16) x parts, wave = head
    k_attn_part<P><<<dim3((N_ / 16) * P, 1, B_), 256, 0, stream>>>(
        adj, mask, featsT, ss, sn, pacc, pZ, pe);
    k_reduce<P><<<dim3(N_ / 64, H_, B_), 256, 0, stream>>>(pacc, pZ, pe, bias,
                                                           act, eloss);
  } else {
    k_attn_direct<<<dim3(N_ / 64, H_, B_), 256, 0, stream>>>(
        adj, mask, featsT, ss, sn, bias, act, eloss);
  }
}

// Round 4
// 221.238 us; speedup vs baseline: 1.2413x; 1.2413x over previous
//
#include <hip/hip_runtime.h>

#define B_ 4
#define N_ 2048
#define F_IN 64
#define H_ 4
#define K_ 64
#define L2E 1.44269504088896f

typedef __attribute__((ext_vector_type(8))) short bf16x8;
typedef __attribute__((ext_vector_type(4))) float f32x4;

__device__ __forceinline__ unsigned short f2bf(float f) {
  unsigned u = __builtin_bit_cast(unsigned, f);
  u = (u + 0x7fffu + ((u >> 16) & 1u)) >> 16;
  return (unsigned short)u;
}

// ---------------------------------------------------------------------------
// Kernel 1: feats = x @ W per head (bf16 MFMA). Outputs:
//  - featsB: MFMA-native swizzled bf16 layout so k_attn B-loads are
//    lane-contiguous:  featsB[(((bh*(N/32)+m32)*4+g)*64 + q*16+rr)*8 + jj]
//    holds feats[n = m32*32 + q*8 + jj][col = g*16+rr].
//  - ss/sn row scores pre-scaled by log2(e).
// ---------------------------------------------------------------------------
#define WT_STRIDE 72

__global__ __launch_bounds__(256) void k_feats(
    const float* __restrict__ x, const float* __restrict__ W,
    const float* __restrict__ a_self, const float* __restrict__ a_neigh,
    unsigned short* __restrict__ featsB, float* __restrict__ ss,
    float* __restrict__ sn) {
  __shared__ __align__(16) unsigned short wt[K_ * WT_STRIDE];  // wt[col][f]
  const int b = blockIdx.z, h = blockIdx.y, n0 = blockIdx.x * 64;
  const int tid = threadIdx.x;
  const float* Wh = W + h * F_IN * K_;
  {
    const int f = tid & 63;
#pragma unroll
    for (int i = 0; i < 16; ++i) {
      const int k = (tid >> 6) + 4 * i;
      wt[k * WT_STRIDE + f] = f2bf(Wh[f * K_ + k]);  // wt[col=k][f]
    }
  }
  __syncthreads();
  const int wave = tid >> 6, lane = tid & 63;
  const int q = lane >> 4, rr = lane & 15;
  const int bh = b * H_ + h;
  const int arow = n0 + wave * 16 + rr;  // A-operand row = lane&15
  const float* xr = x + ((size_t)b * N_ + arow) * F_IN;
  f32x4 x0 = *(const f32x4*)(xr + q * 8);
  f32x4 x1 = *(const f32x4*)(xr + q * 8 + 4);
  f32x4 x2 = *(const f32x4*)(xr + 32 + q * 8);
  f32x4 x3 = *(const f32x4*)(xr + 32 + q * 8 + 4);
  bf16x8 a0, a1;
#pragma unroll
  for (int j = 0; j < 4; ++j) {
    a0[j] = (short)f2bf(x0[j]); a0[j + 4] = (short)f2bf(x1[j]);
    a1[j] = (short)f2bf(x2[j]); a1[j + 4] = (short)f2bf(x3[j]);
  }
  f32x4 acc[4];
#pragma unroll
  for (int c = 0; c < 4; ++c) acc[c] = (f32x4){0.f, 0.f, 0.f, 0.f};
#pragma unroll
  for (int c = 0; c < 4; ++c) {
    bf16x8 b0 = *(const bf16x8*)(&wt[(c * 16 + rr) * WT_STRIDE + q * 8]);
    bf16x8 b1 = *(const bf16x8*)(&wt[(c * 16 + rr) * WT_STRIDE + 32 + q * 8]);
    acc[c] = __builtin_amdgcn_mfma_f32_16x16x32_bf16(a0, b0, acc[c], 0, 0, 0);
    acc[c] = __builtin_amdgcn_mfma_f32_16x16x32_bf16(a1, b1, acc[c], 0, 0, 0);
  }
  // C/D layout: col=c*16+rr, n = n0 + wave*16 + q*4 + t  -> featsB swizzle.
  const int n_base = n0 + wave * 16 + q * 4;
#pragma unroll
  for (int c = 0; c < 4; ++c) {
    ushort4 v;
    v.x = f2bf(acc[c][0]); v.y = f2bf(acc[c][1]);
    v.z = f2bf(acc[c][2]); v.w = f2bf(acc[c][3]);
    const size_t gb = ((size_t)bh * (N_ / 32) + (n_base >> 5)) * 4 + c;
    *(ushort4*)(featsB + (gb * 64 + ((n_base >> 3) & 3) * 16 + rr) * 8 +
                (n_base & 7)) = v;
  }
  float asv[4], anv[4];
#pragma unroll
  for (int c = 0; c < 4; ++c) {
    asv[c] = a_self[h * K_ + c * 16 + rr] * L2E;   // fold log2(e)
    anv[c] = a_neigh[h * K_ + c * 16 + rr] * L2E;
  }
#pragma unroll
  for (int t = 0; t < 4; ++t) {
    float ps = 0.f, pn = 0.f;
#pragma unroll
    for (int c = 0; c < 4; ++c) { ps += acc[c][t] * asv[c]; pn += acc[c][t] * anv[c]; }
#pragma unroll
    for (int off = 8; off > 0; off >>= 1) {
      ps += __shfl_xor(ps, off);
      pn += __shfl_xor(pn, off);
    }
    if (rr == 0) {
      const int n = n0 + wave * 16 + q * 4 + t;
      ss[bh * N_ + n] = ps;
      sn[bh * N_ + n] = pn;
    }
  }
}

// ---------------------------------------------------------------------------
// Kernel 2a: block = (b, part, 16-row tile); wave = head.
// Score phase: lane -> (row=lane>>2, m-quarter=(lane&3)*16): adj/mask f32x4
// loads are fully coalesced (1 line per 4 lanes). wa (bf16) staged through a
// per-wave LDS tile (stride 72 ushort: bank-uniform), re-read in MFMA
// A-fragment order (same wave -> no barrier). featsB loads are lane*16B
// contiguous. Unnormalized single-pass softmax; partials to pacc/pZ/pe.
// ---------------------------------------------------------------------------
#define WA_STRIDE 72

template <int P>
__global__ __launch_bounds__(256) void k_attn_part(
    const float* __restrict__ adj, const float* __restrict__ mask,
    const unsigned short* __restrict__ featsB, const float* __restrict__ ss,
    const float* __restrict__ sn, float* __restrict__ pacc,
    float* __restrict__ pZ, float* __restrict__ pe) {
  constexpr int MSEG = N_ / P;
  __shared__ __align__(16) float sn_lds[H_][MSEG];
  __shared__ __align__(16) unsigned short wa_lds[H_][16][WA_STRIDE];
  const int b = blockIdx.z;
  const int nt = blockIdx.x % (N_ / 16), part = blockIdx.x / (N_ / 16);
  const int tid = threadIdx.x;
  const int mbase = part * MSEG;
  for (int i = tid; i < H_ * MSEG; i += 256) {
    const int hh = i / MSEG, m = i % MSEG;
    sn_lds[hh][m] = sn[(b * H_ + hh) * N_ + mbase + m];
  }
  __syncthreads();
  const int wave = tid >> 6, lane = tid & 63;  // wave = head
  const int bh = b * H_ + wave;
  const int q = lane >> 4, rr = lane & 15;     // MFMA fragment coords
  const int r = lane >> 2, mq4 = (lane & 3) * 16;  // score-phase coords
  const int rb = nt * 16;
  const float ss_r = ss[bh * N_ + rb + r];
  const float* adj_row = adj + ((size_t)b * N_ + rb + r) * N_ + mbase + mq4;
  const float* mask_row = mask + ((size_t)b * N_ + rb + r) * N_ + mbase + mq4;
  unsigned short* wl = &wa_lds[wave][0][0];
  f32x4 acc[4];
#pragma unroll
  for (int g = 0; g < 4; ++g) acc[g] = (f32x4){0.f, 0.f, 0.f, 0.f};
  float Zp = 0.f, ep = 0.f;
  for (int c0 = 0; c0 < MSEG; c0 += 64) {
    f32x4 av[4], mv[4], sv[4];
#pragma unroll
    for (int t = 0; t < 4; ++t) {
      av[t] = *(const f32x4*)(adj_row + c0 + t * 4);
      mv[t] = *(const f32x4*)(mask_row + c0 + t * 4);
      sv[t] = *(const f32x4*)(&sn_lds[wave][c0 + mq4 + t * 4]);
    }
#pragma unroll
    for (int t = 0; t < 4; ++t) {
      unsigned ub[4];
#pragma unroll
      for (int j = 0; j < 4; ++j) {
        float tt = ss_r + sv[t][j];
        float sc = fmaxf(tt, 0.2f * tt);             // leaky (scaled domain)
        float wv = exp2f(fmaf(mv[t][j], L2E, sc));   // e^(orig score)
        Zp += wv;
        float wa = wv * av[t][j];
        ep += wa;
        ub[j] = __builtin_bit_cast(unsigned, wa) + 0x8000u;  // rnd-half-up
      }
      unsigned pk0 = __builtin_amdgcn_perm(ub[1], ub[0], 0x07060302u);
      unsigned pk1 = __builtin_amdgcn_perm(ub[3], ub[2], 0x07060302u);
      *(uint2*)(&wl[r * WA_STRIDE + mq4 + t * 4]) = make_uint2(pk0, pk1);
    }
#pragma unroll
    for (int mh = 0; mh < 2; ++mh) {
      bf16x8 af = *(const bf16x8*)(&wl[rr * WA_STRIDE + mh * 32 + q * 8]);
      const int m32 = ((mbase + c0) >> 5) + mh;
      const unsigned short* fb =
          featsB + (((size_t)bh * (N_ / 32) + m32) * 4 * 64 + lane) * 8;
#pragma unroll
      for (int g = 0; g < 4; ++g) {
        bf16x8 bf = *(const bf16x8*)(fb + (size_t)g * 512);
        acc[g] = __builtin_amdgcn_mfma_f32_16x16x32_bf16(af, bf, acc[g], 0, 0, 0);
      }
    }
  }
  // Z/e: lane holds quarter-row partials; reduce over the 4 lanes of row r.
  Zp += __shfl_xor(Zp, 1); Zp += __shfl_xor(Zp, 2);
  ep += __shfl_xor(ep, 1); ep += __shfl_xor(ep, 2);
  if ((lane & 3) == 0) {
    pZ[(part * 16 + bh) * N_ + rb + r] = Zp;
    pe[(part * 16 + bh) * N_ + rb + r] = ep;
  }
#pragma unroll
  for (int t = 0; t < 4; ++t) {
    const int n = rb + q * 4 + t;  // C/D row = q*4+t
    float* pr = pacc + ((size_t)((part * 16 + bh) * N_ + n)) * 64;
    pr[rr]      = acc[0][t];
    pr[16 + rr] = acc[1][t];
    pr[32 + rr] = acc[2][t];
    pr[48 + rr] = acc[3][t];
  }
}

// ---------------------------------------------------------------------------
// Kernel 2b: combine P partials, normalize, bias + BN + ReLU, e_loss.
// (proven R2/R3) One block per (b,h,64-row tile).
// ---------------------------------------------------------------------------
template <int P>
__global__ __launch_bounds__(256) void k_reduce(
    const float* __restrict__ pacc, const float* __restrict__ pZ,
    const float* __restrict__ pe, const float* __restrict__ bias,
    float* __restrict__ act, float* __restrict__ eloss) {
  const int b = blockIdx.z, h = blockIdx.y, nt = blockIdx.x;
  const int bh = b * H_ + h, tid = threadIdx.x;
  __shared__ float zs[64], es[64];
  if (tid < 64) {
    float z = 0.f, e = 0.f;
#pragma unroll
    for (int p = 0; p < P; ++p) {
      z += pZ[(p * 16 + bh) * N_ + nt * 64 + tid];
      e += pe[(p * 16 + bh) * N_ + nt * 64 + tid];
    }
    zs[tid] = 1.f / z;
    es[tid] = e / z;
  }
  __syncthreads();
  const float INVS = 0.99950037468777323f;  // 1/sqrt(1+1e-3)
#pragma unroll
  for (int ee = 0; ee < 16; ++ee) {
    const int idx = ee * 256 + tid;
    const int rl = idx >> 6, col = idx & 63;
    float v = 0.f;
#pragma unroll
    for (int p = 0; p < P; ++p)
      v += pacc[(((p * 16 + bh) * 32 + nt) << 12) + idx];
    const int n = nt * 64 + rl;
    act[((size_t)(b * N_ + n)) * (H_ * K_) + h * K_ + col] =
        fmaxf(0.f, (v * zs[rl] + bias[h * K_ + col]) * INVS);
  }
  if (tid < 64) {
    float v = es[tid];
#pragma unroll
    for (int off = 32; off > 0; off >>= 1) v += __shfl_xor(v, off);
    if (tid == 0) atomicAdd(eloss + b, v * (1.f / N_));
  }
}

extern "C" void kernel_launch(void* const* d_in, const int* in_sizes, int n_in,
                              void* d_out, int out_size, void* d_ws, size_t ws_size,
                              hipStream_t stream) {
  const float* x      = (const float*)d_in[0];
  const float* adj    = (const float*)d_in[1];
  const float* mask   = (const float*)d_in[2];
  const float* W      = (const float*)d_in[3];
  const float* a_self = (const float*)d_in[4];
  const float* a_neigh= (const float*)d_in[5];
  const float* bias   = (const float*)d_in[6];
  float* act = (float*)d_out;
  float* uloss = act + (size_t)B_ * N_ * H_ * K_;
  float* eloss = uloss + B_;

  const size_t featsBytes = (size_t)B_ * H_ * K_ * N_ * 2;   // 4 MB
  const size_t sBytes = (size_t)B_ * H_ * N_ * 4;            // 128 KB

  unsigned short* featsB = (unsigned short*)d_ws;
  char* pbase = (char*)d_ws + featsBytes;
  float* ss = (float*)pbase;
  float* sn = ss + B_ * H_ * N_;
  char* p4 = pbase + 2 * sBytes;

  auto bytes_for = [&](int P) {
    return featsBytes + 2 * sBytes +
           (size_t)P * B_ * H_ * N_ * 64 * 4 +    // pacc
           2 * (size_t)P * B_ * H_ * N_ * 4;      // pZ + pe
  };

  // u_loss is identically 0 (counts == deg elementwise); also zeroes eloss.
  hipMemsetAsync(uloss, 0, 8 * sizeof(float), stream);

  k_feats<<<dim3(N_ / 64, H_, B_), 256, 0, stream>>>(x, W, a_self, a_neigh,
                                                     featsB, ss, sn);
  if (ws_size >= bytes_for(4)) {
    constexpr int P = 4;
    float* pacc = (float*)p4;
    float* pZ = pacc + (size_t)P * B_ * H_ * N_ * 64;
    float* pe = pZ + (size_t)P * B_ * H_ * N_;
    k_attn_part<P><<<dim3((N_ / 16) * P, 1, B_), 256, 0, stream>>>(
        adj, mask, featsB, ss, sn, pacc, pZ, pe);
    k_reduce<P><<<dim3(N_ / 64, H_, B_), 256, 0, stream>>>(pacc, pZ, pe, bias,
                                                           act, eloss);
  } else {
    constexpr int P = 1;
    float* pacc = (float*)p4;
    float* pZ = pacc + (size_t)P * B_ * H_ * N_ * 64;
    float* pe = pZ + (size_t)P * B_ * H_ * N_;
    k_attn_part<P><<<dim3((N_ / 16) * P, 1, B_), 256, 0, stream>>>(
        adj, mask, featsB, ss, sn, pacc, pZ, pe);
    k_reduce<P><<<dim3(N_ / 64, H_, B_), 256, 0, stream>>>(pacc, pZ, pe, bias,
                                                           act, eloss);
  }
}